// Round 1
// baseline (468.055 us; speedup 1.0000x reference)
//
#include <hip/hip_runtime.h>
#include <hip/hip_bf16.h>

#define B_ 4
#define N_ 1024
#define NB_ 32
#define C_ 384
#define CZ_ 128
#define NSITES (B_ * N_)   // 4096
#define EPSV 1e-6f
#define SPB 2              // sites per block
#define THREADS 512
#define WCHUNK_B 24576     // staged W chunk: 384 cols x 32 k x 2B
#define NKS 12             // k-chunks for W_s (384/32)
#define NKZ 4              // k-chunks for W_z (128/32)

typedef unsigned short u16;
typedef unsigned int u32;
typedef __bf16 bf16x8 __attribute__((ext_vector_type(8)));
typedef float f32x4 __attribute__((ext_vector_type(4)));

__device__ __forceinline__ u16 f2bf(float f) {
    return __builtin_bit_cast(u16, __float2bfloat16(f));
}
__device__ __forceinline__ u32 pk2(float lo, float hi) {
    return ((u32)f2bf(hi) << 16) | f2bf(lo);
}
__device__ __forceinline__ float bfbits2f(u16 u) {
    union { float f; u32 i; } x;
    x.i = ((u32)u) << 16;
    return x.f;
}
__device__ __forceinline__ bf16x8 mk8(float4 lo, float4 hi) {
    union { u32 u[4]; bf16x8 v; } x;
    x.u[0] = pk2(lo.x, lo.y); x.u[1] = pk2(lo.z, lo.w);
    x.u[2] = pk2(hi.x, hi.y); x.u[3] = pk2(hi.z, hi.w);
    return x.v;
}

// Chunk-major workspace, matching the LINEAR global_load_lds write order:
//   ws[((c*4 + q)*384 + d)*8 + e] = bf16(W[k][d]),  k = c*32 + q*8 + e
// so a straight 24576-B DMA of chunk c yields LDS layout [q][d][8]:
// b-frag read at byte (q*6144 + d*16) -> 16 lanes = 256 contiguous bytes
// -> 2 lanes/bank (free).
__global__ void prep_weights(const float* __restrict__ Ws, const float* __restrict__ Wz,
                             u16* __restrict__ wsS, u16* __restrict__ wsZ) {
    int idx = blockIdx.x * 256 + threadIdx.x;
    const int NS = NKS * 4 * C_ * 8;   // 147456
    if (idx < NS) {
        int e = idx & 7, t = idx >> 3;
        int d = t % C_, u = t / C_;
        int q = u & 3, c = u >> 2;
        int k = c * 32 + q * 8 + e;
        wsS[idx] = f2bf(Ws[k * C_ + d]);
    } else {
        int j = idx - NS;
        if (j < NKZ * 4 * C_ * 8) {    // 49152
            int e = j & 7, t = j >> 3;
            int d = t % C_, u = t / C_;
            int q = u & 3, c = u >> 2;
            int k = c * 32 + q * 8 + e;
            wsZ[j] = f2bf(Wz[k * C_ + d]);
        }
    }
}

// Block = 512 thr (8 waves), 2 sites (64 neighbor rows), N=384.
// Wave (mg, ns): mg = site (32 rows as 2 mt-frags), ns = 96-col strip.
// W: double-buffered LDS via global_load_lds (async DMA, conflict-free layout).
// A: direct per-lane global->reg loads (frag-shaped, 128B/row coalesced),
//    packed to bf16 in registers. One barrier per k-chunk.
__global__ __launch_bounds__(THREADS, 4)
void fused_msg_kernel(const float* __restrict__ s_i,
                      const float* __restrict__ s_ij,
                      const float* __restrict__ m_ij,
                      const float* __restrict__ z_ij,
                      const u16* __restrict__ wsS,
                      const u16* __restrict__ wsZ,
                      const float* __restrict__ gamma,
                      const float* __restrict__ beta,
                      float* __restrict__ out) {
    __shared__ u16 ldsW[2][WCHUNK_B / 2];   // 2 x 24576 B
    __shared__ float lds_snew[SPB * C_];    // 3072 B     total 52224 B

    const int tid = threadIdx.x;
    const int wave = tid >> 6;
    const int lane = tid & 63;
    const int q = lane >> 4;
    const int ln = lane & 15;
    const int mg = wave >> 2;            // site within the pair
    const int cb = (wave & 3) * 96;      // column strip base

    const int site0 = blockIdx.x * SPB;
    const long rowbase = (long)site0 * NB_;
    const long arow0 = rowbase + mg * 32 + ln;   // a0 global row

    const float mv = m_ij[rowbase + lane];       // per-lane neighbor mask

    const f32x4 ZERO = {0.f, 0.f, 0.f, 0.f};
    f32x4 acc[2][6];
    #pragma unroll
    for (int mt = 0; mt < 2; ++mt)
        #pragma unroll
        for (int nt = 0; nt < 6; ++nt)
            acc[mt][nt] = ZERO;

    float4 ra[2][4];                      // A staging, ping-pong by chunk parity
    const int ldsq = q * (C_ * 8);        // u16 offset of this lane's k-slot plane

// ---- helpers (textual; all indices static at expansion sites) ----
#define STAGE_W(wsbase, c, buf) do {                                          \
        const char* _s = (const char*)(wsbase) + (c) * WCHUNK_B;              \
        char* _d = (char*)&ldsW[(buf)][0];                                    \
        _Pragma("unroll")                                                     \
        for (int _i = 0; _i < 3; ++_i) {                                      \
            int _o = _i * 8192 + tid * 16;                                    \
            __builtin_amdgcn_global_load_lds(                                 \
                (const __attribute__((address_space(1))) void*)(_s + _o),     \
                (__attribute__((address_space(3))) void*)(_d + _o),           \
                16, 0, 0);                                                    \
        }                                                                     \
    } while (0)

#define LOAD_A(base, kd, c, sl) do {                                          \
        const float* _p0 = (base) + arow0 * (kd) + (c) * 32 + q * 8;          \
        const float* _p1 = _p0 + 16 * (kd);                                   \
        ra[sl][0] = *reinterpret_cast<const float4*>(_p0);                    \
        ra[sl][1] = *reinterpret_cast<const float4*>(_p0 + 4);                \
        ra[sl][2] = *reinterpret_cast<const float4*>(_p1);                    \
        ra[sl][3] = *reinterpret_cast<const float4*>(_p1 + 4);                \
    } while (0)

#define COMPUTE(sl) do {                                                      \
        bf16x8 _a0 = mk8(ra[sl][0], ra[sl][1]);                               \
        bf16x8 _a1 = mk8(ra[sl][2], ra[sl][3]);                               \
        const u16* _lw = &ldsW[sl][ldsq];                                     \
        _Pragma("unroll")                                                     \
        for (int _nt = 0; _nt < 6; ++_nt) {                                   \
            bf16x8 _b = *reinterpret_cast<const bf16x8*>(                     \
                _lw + (cb + _nt * 16 + ln) * 8);                              \
            acc[0][_nt] = __builtin_amdgcn_mfma_f32_16x16x32_bf16(            \
                _a0, _b, acc[0][_nt], 0, 0, 0);                               \
            acc[1][_nt] = __builtin_amdgcn_mfma_f32_16x16x32_bf16(            \
                _a1, _b, acc[1][_nt], 0, 0, 0);                               \
        }                                                                     \
    } while (0)

    // -------- Phase 1: gate = z @ Wz (kd=128, NKZ=4) --------
    STAGE_W(wsZ, 0, 0);
    LOAD_A(z_ij, CZ_, 0, 0);
    __syncthreads();
    #pragma unroll
    for (int c = 0; c < NKZ; ++c) {
        if (c + 1 < NKZ) {
            STAGE_W(wsZ, c + 1, (c + 1) & 1);
            LOAD_A(z_ij, CZ_, c + 1, (c + 1) & 1);
        }
        COMPUTE(c & 1);
        __syncthreads();
    }

    // -------- Phase 2 prologue issued early; gate fold overlaps the DMA ----
    STAGE_W(wsS, 0, 0);
    LOAD_A(s_ij, C_, 0, 0);

    // fold mask into gate, pack bf16, zero acc
    u32 gateb[2][6][2];
    #pragma unroll
    for (int mt = 0; mt < 2; ++mt) {
        int rb = mg * 32 + mt * 16 + q * 4;
        float m0 = __shfl(mv, rb + 0, 64);
        float m1 = __shfl(mv, rb + 1, 64);
        float m2 = __shfl(mv, rb + 2, 64);
        float m3 = __shfl(mv, rb + 3, 64);
        #pragma unroll
        for (int nt = 0; nt < 6; ++nt) {
            gateb[mt][nt][0] = pk2(acc[mt][nt][0] * m0, acc[mt][nt][1] * m1);
            gateb[mt][nt][1] = pk2(acc[mt][nt][2] * m2, acc[mt][nt][3] * m3);
            acc[mt][nt] = ZERO;
        }
    }
    __syncthreads();

    // -------- Phase 2: s_proj = s @ Ws (kd=384, NKS=12) --------
    #pragma unroll
    for (int c = 0; c < NKS; ++c) {
        if (c + 1 < NKS) {
            STAGE_W(wsS, c + 1, (c + 1) & 1);
            LOAD_A(s_ij, C_, c + 1, (c + 1) & 1);
        }
        COMPUTE(c & 1);
        __syncthreads();
    }

#undef STAGE_W
#undef LOAD_A
#undef COMPUTE

    // -------- Epilogue: msg + neighbor reduction --------
    // acc row = mg*32 + mt*16 + q*4 + r; col = cb + nt*16 + ln
    #pragma unroll
    for (int nt = 0; nt < 6; ++nt) {
        int col = cb + nt * 16 + ln;
        float si = s_i[(long)(site0 + mg) * C_ + col];
        float p = 0.f;
        #pragma unroll
        for (int mt = 0; mt < 2; ++mt) {
            #pragma unroll
            for (int r = 0; r < 4; ++r) {
                float g = bfbits2f((u16)(gateb[mt][nt][r >> 1] >> ((r & 1) * 16)));
                p += (acc[mt][nt][r] - si) * g;
            }
        }
        p += __shfl_xor(p, 16, 64);
        p += __shfl_xor(p, 32, 64);
        if (q == 0) lds_snew[mg * C_ + col] = p;
    }
    __syncthreads();

    // -------- LayerNorm: wave 0 -> site0, wave 1 -> site1 --------
    if (wave < SPB) {
        const int site = wave;
        float v[6];
        float sum = 0.f, sumsq = 0.f;
        #pragma unroll
        for (int i = 0; i < 6; ++i) {
            v[i] = lds_snew[site * C_ + lane + i * 64];
            sum += v[i];
            sumsq += v[i] * v[i];
        }
        #pragma unroll
        for (int off = 32; off >= 1; off >>= 1) {
            sum += __shfl_xor(sum, off, 64);
            sumsq += __shfl_xor(sumsq, off, 64);
        }
        float mu = sum * (1.f / C_);
        float var = sumsq * (1.f / C_) - mu * mu;
        float rs = rsqrtf(var + EPSV);
        #pragma unroll
        for (int i = 0; i < 6; ++i) {
            int col = lane + i * 64;
            out[(long)(site0 + site) * C_ + col] = (v[i] - mu) * rs * gamma[col] + beta[col];
        }
    }
}

extern "C" void kernel_launch(void* const* d_in, const int* in_sizes, int n_in,
                              void* d_out, int out_size, void* d_ws, size_t ws_size,
                              hipStream_t stream) {
    (void)in_sizes; (void)n_in; (void)out_size; (void)ws_size;
    const float* s_i   = (const float*)d_in[0];
    const float* s_ij  = (const float*)d_in[1];
    const float* m_ij  = (const float*)d_in[2];
    const float* z_ij  = (const float*)d_in[3];
    const float* W_s   = (const float*)d_in[4];
    const float* W_z   = (const float*)d_in[5];
    const float* gamma = (const float*)d_in[6];
    const float* beta  = (const float*)d_in[7];
    float* out = (float*)d_out;

    u16* wsS = (u16*)d_ws;                  // 12 chunks x 24576 B
    u16* wsZ = wsS + NKS * 4 * C_ * 8;      //  4 chunks x 24576 B

    int prep_elems = NKS * 4 * C_ * 8 + NKZ * 4 * C_ * 8;   // 196608
    prep_weights<<<(prep_elems + 255) / 256, 256, 0, stream>>>(W_s, W_z, wsS, wsZ);
    fused_msg_kernel<<<NSITES / SPB, THREADS, 0, stream>>>(s_i, s_ij, m_ij, z_ij,
                                                           wsS, wsZ, gamma, beta, out);
}